// Round 8
// baseline (258.795 us; speedup 1.0000x reference)
//
#include <hip/hip_runtime.h>

#define B_ 2
#define S_ 2048
#define DM_ 1024
#define H_ 16
#define HD_ 64
#define SCALE_ 0.125f

// Settled R0-R4: inputs fp32 (bf16-rounded values), output fp32.
typedef __bf16 bf16;
typedef __attribute__((ext_vector_type(4))) __bf16 bf16x4;
typedef __attribute__((ext_vector_type(8))) __bf16 bf16x8;
typedef __attribute__((ext_vector_type(4))) float f32x4;

#define MFMA16(a, b, c) __builtin_amdgcn_mfma_f32_16x16x32_bf16((a), (b), (c), 0, 0, 0)

__device__ __forceinline__ void async16(const bf16* g, bf16* l) {
  __builtin_amdgcn_global_load_lds(
      (const __attribute__((address_space(1))) void*)g,
      (__attribute__((address_space(3))) void*)l, 16, 0, 0);
}

// ---------------------------------------------------------------------------
// Convert pass: fp32 -> bf16, activations (3x4M) + weights (4x1M).
// ---------------------------------------------------------------------------
__global__ __launch_bounds__(256) void convert_kernel(
    const float* __restrict__ q, const float* __restrict__ k,
    const float* __restrict__ v, const float* __restrict__ wq,
    const float* __restrict__ wk, const float* __restrict__ wv,
    const float* __restrict__ wo, bf16* __restrict__ dst) {
  size_t idx = ((size_t)blockIdx.x * 256 + threadIdx.x) * 8;
  const float* src;
  size_t off;
  if (idx < 4194304) { src = q; off = idx; }
  else if (idx < 8388608) { src = k; off = idx - 4194304; }
  else if (idx < 12582912) { src = v; off = idx - 8388608; }
  else if (idx < 13631488) { src = wq; off = idx - 12582912; }
  else if (idx < 14680064) { src = wk; off = idx - 13631488; }
  else if (idx < 15728640) { src = wv; off = idx - 14680064; }
  else { src = wo; off = idx - 15728640; }
  float4 a = *(const float4*)(src + off);
  float4 b = *(const float4*)(src + off + 4);
  bf16x8 o;
  o[0] = (bf16)a.x; o[1] = (bf16)a.y; o[2] = (bf16)a.z; o[3] = (bf16)a.w;
  o[4] = (bf16)b.x; o[5] = (bf16)b.y; o[6] = (bf16)b.z; o[7] = (bf16)b.w;
  *(bf16x8*)(dst + idx) = o;
}

// ---------------------------------------------------------------------------
// GEMM 128x128 (m97 structure): C = A[4096][1024] @ W[1024][1024]^T + bias.
// MODE 1: scatter to [B,H,S,HD] bf16
// MODE 2: V^T [B,H,HD,S] bf16 via LDS transpose + coalesced 16B stores
// ---------------------------------------------------------------------------
template <int MODE>
__device__ __forceinline__ void gemm_body(const bf16* A, const bf16* W,
                                          const float* bias, bf16* C,
                                          float scale) {
  constexpr int K = 1024;
  __shared__ __align__(16) bf16 As[128 * 32];
  __shared__ __align__(16) bf16 Bs[128 * 32];
  const int t = threadIdx.x;
  const int lane = t & 63, wave = t >> 6;
  const int quad = lane >> 4, l16 = lane & 15;
  const int m0 = blockIdx.y * 128, n0 = blockIdx.x * 128;
  const int wm = (wave >> 1) * 64, wn = (wave & 1) * 64;

  const f32x4 zero = {0.f, 0.f, 0.f, 0.f};
  f32x4 acc[4][4];
  for (int i = 0; i < 4; i++)
    for (int j = 0; j < 4; j++) acc[i][j] = zero;

  for (int k0 = 0; k0 < K; k0 += 32) {
    for (int i = 0; i < 2; ++i) {
      int c = i * 256 + t;
      int row = c >> 2, kc = (c & 3) * 8;
      async16(A + (size_t)(m0 + row) * K + k0 + kc, As + c * 8);
      async16(W + (size_t)(n0 + row) * K + k0 + kc, Bs + c * 8);
    }
    __syncthreads();

    bf16x8 af[4], bfr[4];
    for (int mb = 0; mb < 4; mb++) {
      af[mb] = *(const bf16x8*)(As + (wm + mb * 16 + l16) * 32 + quad * 8);
      bfr[mb] = *(const bf16x8*)(Bs + (wn + mb * 16 + l16) * 32 + quad * 8);
    }
    for (int mb = 0; mb < 4; mb++)
      for (int nb = 0; nb < 4; nb++)
        acc[mb][nb] = MFMA16(af[mb], bfr[nb], acc[mb][nb]);
    __syncthreads();
  }

  if constexpr (MODE == 2) {
    // transpose through LDS: Ct[col][row], row-stride 136
    __shared__ __align__(16) bf16 Ct[128 * 136];
    for (int nb = 0; nb < 4; nb++) {
      int cl = wn + nb * 16 + l16;
      float bv = bias[n0 + cl] * scale;
      for (int mb = 0; mb < 4; mb++) {
        int rowb = wm + mb * 16 + quad * 4;
        bf16x4 v;
        for (int r = 0; r < 4; r++)
          v[r] = (bf16)(acc[mb][nb][r] * scale + bv);
        *(bf16x4*)(Ct + cl * 136 + rowb) = v;
      }
    }
    __syncthreads();
    int c = t >> 1, half = t & 1;
    int colg = n0 + c;
    int hh = colg >> 6, dd = colg & 63;
    int bb = m0 >> 11, s0 = m0 & (S_ - 1);
    bf16* dst = C + (((size_t)(bb * H_ + hh)) * HD_ + dd) * S_ + s0 + half * 64;
    const bf16* srcr = Ct + c * 136 + half * 64;
    for (int j = 0; j < 8; ++j)
      *(bf16x8*)(dst + j * 8) = *(const bf16x8*)(srcr + j * 8);
  } else {
    for (int nb = 0; nb < 4; nb++) {
      int col = n0 + wn + nb * 16 + l16;
      float bv = bias[col] * scale;
      for (int mb = 0; mb < 4; mb++) {
        int rowb = m0 + wm + mb * 16 + quad * 4;
        for (int r = 0; r < 4; r++) {
          int row = rowb + r;
          float o = acc[mb][nb][r] * scale + bv;
          int bb = row >> 11, s = row & (S_ - 1);
          int h = col >> 6, d = col & 63;
          C[(((size_t)(bb * H_ + h)) * S_ + s) * HD_ + d] = (bf16)o;
        }
      }
    }
  }
}

__global__ __launch_bounds__(256) void qkv_proj_kernel(
    const bf16* Xc, const float* bq, const float* bk, const float* bv,
    bf16* Qo, bf16* Ko, bf16* Vo) {
  int z = blockIdx.z;
  const bf16* A = Xc + (size_t)z * 4194304;
  const bf16* W = Xc + 12582912 + (size_t)z * 1048576;
  if (z == 0)
    gemm_body<1>(A, W, bq, Qo, SCALE_);  // Q pre-scaled (exact 2^-3)
  else if (z == 1)
    gemm_body<1>(A, W, bk, Ko, 1.0f);
  else
    gemm_body<2>(A, W, bv, Vo, 1.0f);
}

// ---------------------------------------------------------------------------
// out_proj: 64x128 tiles -> 512 blocks (R7's 128x128 gave 256 blocks = 1
// block/CU = no inter-block overlap of the staging barrier drain).
// Each wave: 16 rows x 128 cols.
// ---------------------------------------------------------------------------
__global__ __launch_bounds__(256) void out_proj_kernel(const bf16* A,
                                                       const bf16* W,
                                                       const float* bias,
                                                       float* C) {
  constexpr int K = 1024, N = 1024;
  __shared__ __align__(16) bf16 As[64 * 32];
  __shared__ __align__(16) bf16 Bs[128 * 32];
  const int t = threadIdx.x;
  const int lane = t & 63, wave = t >> 6;
  const int quad = lane >> 4, l16 = lane & 15;
  const int m0 = blockIdx.y * 64, n0 = blockIdx.x * 128;

  const f32x4 zero = {0.f, 0.f, 0.f, 0.f};
  f32x4 acc[8];
  for (int i = 0; i < 8; i++) acc[i] = zero;

  for (int k0 = 0; k0 < K; k0 += 32) {
    {
      int row = t >> 2, kc = (t & 3) * 8;
      async16(A + (size_t)(m0 + row) * K + k0 + kc, As + t * 8);
    }
    for (int i = 0; i < 2; ++i) {
      int c = i * 256 + t;
      int row = c >> 2, kc = (c & 3) * 8;
      async16(W + (size_t)(n0 + row) * K + k0 + kc, Bs + c * 8);
    }
    __syncthreads();

    bf16x8 af = *(const bf16x8*)(As + (wave * 16 + l16) * 32 + quad * 8);
    for (int nb = 0; nb < 8; nb++) {
      bf16x8 bfr = *(const bf16x8*)(Bs + (nb * 16 + l16) * 32 + quad * 8);
      acc[nb] = MFMA16(af, bfr, acc[nb]);
    }
    __syncthreads();
  }

  for (int nb = 0; nb < 8; nb++) {
    int col = n0 + nb * 16 + l16;
    float bv = bias[col];
    int rowb = m0 + wave * 16 + quad * 4;
    for (int r = 0; r < 4; r++)
      C[(size_t)(rowb + r) * N + col] = acc[nb][r] + bv;
  }
}

// ---------------------------------------------------------------------------
// Flash attention, softmax-one, S^T order. Block = (b,h,64 q-rows), 4 waves
// x 16 q-rows. KV tiles 128. 1024 blocks; LDS 50KB -> 3 blocks/CU (R7: 512
// blocks/66KB = 2/CU, occupancy 18.7% -> latency-bound). XCD-swizzled decode:
// id&31 -> (b,h), so each XCD's L2 holds only 4 KV sets (~2MB, resident).
// No max-tracking (|scores| bounded ~3); softmax-one denom = 1 + sum.
// ---------------------------------------------------------------------------
__global__ __launch_bounds__(256) void attn_kernel(const bf16* __restrict__ Q,
                                                   const bf16* __restrict__ Kg,
                                                   const bf16* __restrict__ VTg,
                                                   bf16* __restrict__ O) {
  __shared__ __align__(16) bf16 Ks[128 * 64];     // XOR-swizzled granules
  __shared__ __align__(16) bf16 Vt[64 * 128];     // XOR-swizzled granules
  __shared__ __align__(16) bf16 Ps[4 * 16 * 136]; // per-wave P^T, padded
  const int t = threadIdx.x;
  const int lane = t & 63, wave = t >> 6;
  const int quad = lane >> 4, l16 = lane & 15;
  const int id = blockIdx.x;
  const int bh = id & 31;   // (b,h): fixes XCD class (id%8 = bh%8)
  const int q0 = (id >> 5) * 64;
  const int b = bh >> 4, h = bh & 15;
  const size_t base = ((size_t)(b * H_ + h)) * S_ * HD_;
  const bf16* Qp = Q + base;
  const bf16* Kp = Kg + base;
  const bf16* Vp = VTg + base;  // [HD][S]

  // Q fragments (B-operand), rows q0 + wave*16 + l16
  bf16x8 aq0, aq1;
  {
    const bf16* qr = Qp + (size_t)(q0 + wave * 16 + l16) * HD_;
    aq0 = *(const bf16x8*)(qr + quad * 8);
    aq1 = *(const bf16x8*)(qr + 32 + quad * 8);
  }

  const f32x4 zero = {0.f, 0.f, 0.f, 0.f};
  f32x4 oc[4];
  for (int d = 0; d < 4; d++) oc[d] = zero;
  float rs = 0.f;

  bf16* Pw = Ps + wave * (16 * 136);

  for (int kv0 = 0; kv0 < S_; kv0 += 128) {
    // stage K tile: LDS slot (row,g) <- global granule (row, g^(row&7))
    for (int i = 0; i < 4; ++i) {
      int c = i * 256 + t;
      int row = c >> 3, g = c & 7;
      async16(Kp + (size_t)(kv0 + row) * HD_ + (g ^ (row & 7)) * 8, Ks + c * 8);
    }
    // stage V^T tile: slot (d,g) <- global granule (d, g^(d&15))
    for (int i = 0; i < 4; ++i) {
      int c = i * 256 + t;
      int d = c >> 4, g = c & 15;
      async16(Vp + (size_t)d * S_ + kv0 + (g ^ (d & 15)) * 8, Vt + c * 8);
    }
    __syncthreads();

    // S^T = K Q^T: sc[nb][r] = S[key=kv0+nb*16+quad*4+r][q=l16]
    f32x4 sc[8];
    for (int nb = 0; nb < 8; nb++) sc[nb] = zero;
    for (int ks = 0; ks < 2; ks++) {
      bf16x8 qf = ks ? aq1 : aq0;
      for (int nb = 0; nb < 8; nb++) {
        int row = nb * 16 + l16;
        int slot = (ks * 4 + quad) ^ (row & 7);
        bf16x8 kf = *(const bf16x8*)(Ks + row * 64 + slot * 8);
        sc[nb] = MFMA16(kf, qf, sc[nb]);
      }
    }

    // exp + packed P^T write + per-lane partial sum (no shuffles, no max)
    bf16* prow = Pw + l16 * 136 + quad * 4;
    for (int nb = 0; nb < 8; nb++) {
      float p0 = __expf(sc[nb][0]);
      float p1 = __expf(sc[nb][1]);
      float p2 = __expf(sc[nb][2]);
      float p3 = __expf(sc[nb][3]);
      rs += (p0 + p1) + (p2 + p3);
      bf16x4 pv = {(bf16)p0, (bf16)p1, (bf16)p2, (bf16)p3};
      *(bf16x4*)(prow + nb * 16) = pv;
    }
    // Pw is wave-private; same-wave DS ordering suffices (no barrier).

    // O += P V
    for (int ks = 0; ks < 4; ks++) {
      bf16x8 ap = *(const bf16x8*)(Pw + l16 * 136 + ks * 32 + quad * 8);
      for (int db = 0; db < 4; db++) {
        int row = db * 16 + l16;
        int slot = (ks * 4 + quad) ^ (row & 15);
        bf16x8 vf = *(const bf16x8*)(Vt + row * 128 + slot * 8);
        oc[db] = MFMA16(ap, vf, oc[db]);
      }
    }
    __syncthreads();  // protect Ks/Vt before next tile's staging
  }

  // epilogue: l(q) = 1 + sum over keys; quad-reduce then per-row broadcast
  float rtot = rs;
  rtot += __shfl_xor(rtot, 16);
  rtot += __shfl_xor(rtot, 32);
  float l_all = 1.f + rtot;  // valid for q = l16 (any quad)
  for (int r = 0; r < 4; r++) {
    float inv = 1.f / __shfl(l_all, quad * 4 + r);
    int qrow = q0 + wave * 16 + quad * 4 + r;
    size_t orow = ((size_t)(b * S_ + qrow) * H_ + h) * HD_;
    for (int db = 0; db < 4; db++)
      O[orow + db * 16 + l16] = (bf16)(oc[db][r] * inv);
  }
}

// ---------------------------------------------------------------------------
extern "C" void kernel_launch(void* const* d_in, const int* in_sizes, int n_in,
                              void* d_out, int out_size, void* d_ws,
                              size_t ws_size, hipStream_t stream) {
  const float* query = (const float*)d_in[0];
  const float* key = (const float*)d_in[1];
  const float* value = (const float*)d_in[2];
  const float* bq = (const float*)d_in[4];
  const float* bk = (const float*)d_in[6];
  const float* bv = (const float*)d_in[8];
  const float* bo = (const float*)d_in[10];
  float* out = (float*)d_out;

  // ws layout (bf16 elems): Xc[16.7M] | Qw[4M] | Kw[4M] | Vw[4M] | Ow[4M]
  bf16* Xc = (bf16*)d_ws;
  bf16* Qw = Xc + 16777216;
  const size_t SZ = (size_t)B_ * H_ * S_ * HD_;  // 4M
  bf16* Kw = Qw + SZ;
  bf16* Vw = Kw + SZ;  // V^T, [B,H,HD,S]
  bf16* Ow = Vw + SZ;  // [B,S,H,HD]

  convert_kernel<<<8192, 256, 0, stream>>>(query, key, value,
                                           (const float*)d_in[3],
                                           (const float*)d_in[5],
                                           (const float*)d_in[7],
                                           (const float*)d_in[9], Xc);
  qkv_proj_kernel<<<dim3(8, 32, 3), 256, 0, stream>>>(Xc, bq, bk, bv, Qw, Kw,
                                                      Vw);
  attn_kernel<<<1024, 256, 0, stream>>>(Qw, Kw, Vw, Ow);
  out_proj_kernel<<<dim3(8, 64), 256, 0, stream>>>(Ow, Xc + 15728640, bo, out);
}

// Round 10
// 249.490 us; speedup vs baseline: 1.0373x; 1.0373x over previous
//
#include <hip/hip_runtime.h>

#define B_ 2
#define S_ 2048
#define DM_ 1024
#define H_ 16
#define HD_ 64
// Q pre-scale = HD^-0.5 * log2(e) so attention uses exp2 (bare v_exp_f32).
#define QSCALE_ 0.18033688011112042f

// Settled R0-R4: inputs fp32 (bf16-rounded values), output fp32.
typedef __bf16 bf16;
typedef __attribute__((ext_vector_type(4))) __bf16 bf16x4;
typedef __attribute__((ext_vector_type(8))) __bf16 bf16x8;
typedef __attribute__((ext_vector_type(4))) float f32x4;

#define MFMA16(a, b, c) __builtin_amdgcn_mfma_f32_16x16x32_bf16((a), (b), (c), 0, 0, 0)
#define EXP2(x) __builtin_amdgcn_exp2f(x)

__device__ __forceinline__ void async16(const bf16* g, bf16* l) {
  __builtin_amdgcn_global_load_lds(
      (const __attribute__((address_space(1))) void*)g,
      (__attribute__((address_space(3))) void*)l, 16, 0, 0);
}

// ---------------------------------------------------------------------------
// Convert pass: fp32 -> bf16, activations (3x4M) + weights (4x1M).
// ---------------------------------------------------------------------------
__global__ __launch_bounds__(256) void convert_kernel(
    const float* __restrict__ q, const float* __restrict__ k,
    const float* __restrict__ v, const float* __restrict__ wq,
    const float* __restrict__ wk, const float* __restrict__ wv,
    const float* __restrict__ wo, bf16* __restrict__ dst) {
  size_t idx = ((size_t)blockIdx.x * 256 + threadIdx.x) * 8;
  const float* src;
  size_t off;
  if (idx < 4194304) { src = q; off = idx; }
  else if (idx < 8388608) { src = k; off = idx - 4194304; }
  else if (idx < 12582912) { src = v; off = idx - 8388608; }
  else if (idx < 13631488) { src = wq; off = idx - 12582912; }
  else if (idx < 14680064) { src = wk; off = idx - 13631488; }
  else if (idx < 15728640) { src = wv; off = idx - 14680064; }
  else { src = wo; off = idx - 15728640; }
  float4 a = *(const float4*)(src + off);
  float4 b = *(const float4*)(src + off + 4);
  bf16x8 o;
  o[0] = (bf16)a.x; o[1] = (bf16)a.y; o[2] = (bf16)a.z; o[3] = (bf16)a.w;
  o[4] = (bf16)b.x; o[5] = (bf16)b.y; o[6] = (bf16)b.z; o[7] = (bf16)b.w;
  *(bf16x8*)(dst + idx) = o;
}

// ---------------------------------------------------------------------------
// GEMM 128x128, BK=64, XOR-swizzled LDS (slot g holds granule g^(row&7)):
// kills the ~8-way fragment-read bank aliasing m98 measured on the BK=32
// layout (1.7e7 conflict-cycles ~ 17%), and halves barrier drains (16 vs 32).
// MODE 1: scatter to [B,H,S,HD] bf16.  MODE 2: V^T [B,H,HD,S] bf16 via LDS
// transpose + coalesced 16B stores.
// ---------------------------------------------------------------------------
template <int MODE>
__device__ __forceinline__ void gemm_body(const bf16* A, const bf16* W,
                                          const float* bias, bf16* C,
                                          float scale) {
  constexpr int K = 1024;
  __shared__ __align__(16) bf16 As[128 * 64];
  __shared__ __align__(16) bf16 Bs[128 * 64];
  const int t = threadIdx.x;
  const int lane = t & 63, wave = t >> 6;
  const int quad = lane >> 4, l16 = lane & 15;
  const int m0 = blockIdx.y * 128, n0 = blockIdx.x * 128;
  const int wm = (wave >> 1) * 64, wn = (wave & 1) * 64;

  const f32x4 zero = {0.f, 0.f, 0.f, 0.f};
  f32x4 acc[4][4];
  for (int i = 0; i < 4; i++)
    for (int j = 0; j < 4; j++) acc[i][j] = zero;

  for (int k0 = 0; k0 < K; k0 += 64) {
    for (int i = 0; i < 4; ++i) {
      int c = i * 256 + t;
      int row = c >> 3, g = c & 7;
      int off = k0 + ((g ^ (row & 7)) * 8);
      async16(A + (size_t)(m0 + row) * K + off, As + c * 8);
      async16(W + (size_t)(n0 + row) * K + off, Bs + c * 8);
    }
    __syncthreads();

    for (int ks = 0; ks < 2; ks++) {
      bf16x8 af[4], bfr[4];
      for (int mb = 0; mb < 4; mb++) {
        int ra = wm + mb * 16 + l16;
        af[mb] = *(const bf16x8*)(As + ra * 64 + ((ks * 4 + quad) ^ (ra & 7)) * 8);
        int rb = wn + mb * 16 + l16;
        bfr[mb] = *(const bf16x8*)(Bs + rb * 64 + ((ks * 4 + quad) ^ (rb & 7)) * 8);
      }
      for (int mb = 0; mb < 4; mb++)
        for (int nb = 0; nb < 4; nb++)
          acc[mb][nb] = MFMA16(af[mb], bfr[nb], acc[mb][nb]);
    }
    __syncthreads();
  }

  if constexpr (MODE == 2) {
    __shared__ __align__(16) bf16 Ct[128 * 136];
    for (int nb = 0; nb < 4; nb++) {
      int cl = wn + nb * 16 + l16;
      float bv = bias[n0 + cl] * scale;
      for (int mb = 0; mb < 4; mb++) {
        int rowb = wm + mb * 16 + quad * 4;
        bf16x4 v;
        for (int r = 0; r < 4; r++)
          v[r] = (bf16)(acc[mb][nb][r] * scale + bv);
        *(bf16x4*)(Ct + cl * 136 + rowb) = v;
      }
    }
    __syncthreads();
    int c = t >> 1, half = t & 1;
    int colg = n0 + c;
    int hh = colg >> 6, dd = colg & 63;
    int bb = m0 >> 11, s0 = m0 & (S_ - 1);
    bf16* dst = C + (((size_t)(bb * H_ + hh)) * HD_ + dd) * S_ + s0 + half * 64;
    const bf16* srcr = Ct + c * 136 + half * 64;
    for (int j = 0; j < 8; ++j)
      *(bf16x8*)(dst + j * 8) = *(const bf16x8*)(srcr + j * 8);
  } else {
    for (int nb = 0; nb < 4; nb++) {
      int col = n0 + wn + nb * 16 + l16;
      float bv = bias[col] * scale;
      for (int mb = 0; mb < 4; mb++) {
        int rowb = m0 + wm + mb * 16 + quad * 4;
        for (int r = 0; r < 4; r++) {
          int row = rowb + r;
          float o = acc[mb][nb][r] * scale + bv;
          int bb = row >> 11, s = row & (S_ - 1);
          int h = col >> 6, d = col & 63;
          C[(((size_t)(bb * H_ + h)) * S_ + s) * HD_ + d] = (bf16)o;
        }
      }
    }
  }
}

__global__ __launch_bounds__(256) void qkv_proj_kernel(
    const bf16* Xc, const float* bq, const float* bk, const float* bv,
    bf16* Qo, bf16* Ko, bf16* Vo) {
  int z = blockIdx.z;
  const bf16* A = Xc + (size_t)z * 4194304;
  const bf16* W = Xc + 12582912 + (size_t)z * 1048576;
  if (z == 0)
    gemm_body<1>(A, W, bq, Qo, QSCALE_);  // Q pre-scaled incl. log2(e)
  else if (z == 1)
    gemm_body<1>(A, W, bk, Ko, 1.0f);
  else
    gemm_body<2>(A, W, bv, Vo, 1.0f);
}

// ---------------------------------------------------------------------------
// out_proj: 64x128 tiles (512 blocks), BK=64, swizzled.
// ---------------------------------------------------------------------------
__global__ __launch_bounds__(256) void out_proj_kernel(const bf16* A,
                                                       const bf16* W,
                                                       const float* bias,
                                                       float* C) {
  constexpr int K = 1024, N = 1024;
  __shared__ __align__(16) bf16 As[64 * 64];
  __shared__ __align__(16) bf16 Bs[128 * 64];
  const int t = threadIdx.x;
  const int lane = t & 63, wave = t >> 6;
  const int quad = lane >> 4, l16 = lane & 15;
  const int m0 = blockIdx.y * 64, n0 = blockIdx.x * 128;

  const f32x4 zero = {0.f, 0.f, 0.f, 0.f};
  f32x4 acc[8];
  for (int i = 0; i < 8; i++) acc[i] = zero;

  for (int k0 = 0; k0 < K; k0 += 64) {
    for (int i = 0; i < 2; ++i) {
      int c = i * 256 + t;
      int row = c >> 3, g = c & 7;
      async16(A + (size_t)(m0 + row) * K + k0 + ((g ^ (row & 7)) * 8),
              As + c * 8);
    }
    for (int i = 0; i < 4; ++i) {
      int c = i * 256 + t;
      int row = c >> 3, g = c & 7;
      async16(W + (size_t)(n0 + row) * K + k0 + ((g ^ (row & 7)) * 8),
              Bs + c * 8);
    }
    __syncthreads();

    for (int ks = 0; ks < 2; ks++) {
      int ra = wave * 16 + l16;
      bf16x8 af = *(const bf16x8*)(As + ra * 64 + ((ks * 4 + quad) ^ (ra & 7)) * 8);
      for (int nb = 0; nb < 8; nb++) {
        int rb = nb * 16 + l16;
        bf16x8 bfr =
            *(const bf16x8*)(Bs + rb * 64 + ((ks * 4 + quad) ^ (rb & 7)) * 8);
        acc[nb] = MFMA16(af, bfr, acc[nb]);
      }
    }
    __syncthreads();
  }

  for (int nb = 0; nb < 8; nb++) {
    int col = n0 + nb * 16 + l16;
    float bv = bias[col];
    int rowb = m0 + wave * 16 + quad * 4;
    for (int r = 0; r < 4; r++)
      C[(size_t)(rowb + r) * N + col] = acc[nb][r] + bv;
  }
}

// ---------------------------------------------------------------------------
// Flash attention, softmax-one, S^T order. Block = (b,h,128 q-rows), 4 waves
// x 32 q (2 qsets). KV tiles 128. 512 blocks (R8's 64q/1024-block split
// regressed: staging doubled per unit work -- K/V reuse beats occupancy).
// XCD-swizzled decode (id&31 -> (b,h)): per-XCD KV working set ~2MB, L2
// resident (R8: FETCH 70->12MB, keep). exp2 (Q pre-scaled by log2e); no
// max-tracking (|scores| bounded); softmax-one denom = 1 + sum.
// ---------------------------------------------------------------------------
__global__ __launch_bounds__(256) void attn_kernel(const bf16* __restrict__ Q,
                                                   const bf16* __restrict__ Kg,
                                                   const bf16* __restrict__ VTg,
                                                   bf16* __restrict__ O) {
  __shared__ __align__(16) bf16 Ks[128 * 64];      // XOR-swizzled granules
  __shared__ __align__(16) bf16 Vt[64 * 128];      // XOR-swizzled granules
  __shared__ __align__(16) bf16 Ps[4 * 32 * 136];  // per-wave P^T, padded
  const int t = threadIdx.x;
  const int lane = t & 63, wave = t >> 6;
  const int quad = lane >> 4, l16 = lane & 15;
  const int id = blockIdx.x;
  const int bh = id & 31;  // (b,h): fixes XCD class (id%8 = bh%8)
  const int q0 = (id >> 5) * 128;
  const int b = bh >> 4, h = bh & 15;
  const size_t base = ((size_t)(b * H_ + h)) * S_ * HD_;
  const bf16* Qp = Q + base;
  const bf16* Kp = Kg + base;
  const bf16* Vp = VTg + base;  // [HD][S]

  bf16x8 aq[2][2];
  for (int s = 0; s < 2; s++) {
    const bf16* qr = Qp + (size_t)(q0 + wave * 32 + s * 16 + l16) * HD_;
    aq[s][0] = *(const bf16x8*)(qr + quad * 8);
    aq[s][1] = *(const bf16x8*)(qr + 32 + quad * 8);
  }

  const f32x4 zero = {0.f, 0.f, 0.f, 0.f};
  f32x4 oc[2][4];
  for (int s = 0; s < 2; s++)
    for (int d = 0; d < 4; d++) oc[s][d] = zero;
  float rs[2] = {0.f, 0.f};

  bf16* Pw = Ps + wave * (32 * 136);

  for (int kv0 = 0; kv0 < S_; kv0 += 128) {
    for (int i = 0; i < 4; ++i) {
      int c = i * 256 + t;
      int row = c >> 3, g = c & 7;
      async16(Kp + (size_t)(kv0 + row) * HD_ + (g ^ (row & 7)) * 8, Ks + c * 8);
    }
    for (int i = 0; i < 4; ++i) {
      int c = i * 256 + t;
      int d = c >> 4, g = c & 15;
      async16(Vp + (size_t)d * S_ + kv0 + (g ^ (d & 15)) * 8, Vt + c * 8);
    }
    __syncthreads();

    // S^T = K Q^T: sc[s][nb][r] = S[key=kv0+nb*16+quad*4+r][q = qset s, l16]
    f32x4 sc[2][8];
    for (int s = 0; s < 2; s++)
      for (int nb = 0; nb < 8; nb++) sc[s][nb] = zero;
    for (int ks = 0; ks < 2; ks++) {
      for (int nb = 0; nb < 8; nb++) {
        int row = nb * 16 + l16;
        int slot = (ks * 4 + quad) ^ (row & 7);
        bf16x8 kf = *(const bf16x8*)(Ks + row * 64 + slot * 8);
        sc[0][nb] = MFMA16(kf, aq[0][ks], sc[0][nb]);
        sc[1][nb] = MFMA16(kf, aq[1][ks], sc[1][nb]);
      }
    }

    // exp2 + packed P^T write + per-lane partial sum (no shuffles, no max)
    for (int s = 0; s < 2; s++) {
      bf16* prow = Pw + (s * 16 + l16) * 136 + quad * 4;
      for (int nb = 0; nb < 8; nb++) {
        float p0 = EXP2(sc[s][nb][0]);
        float p1 = EXP2(sc[s][nb][1]);
        float p2 = EXP2(sc[s][nb][2]);
        float p3 = EXP2(sc[s][nb][3]);
        rs[s] += (p0 + p1) + (p2 + p3);
        bf16x4 pv = {(bf16)p0, (bf16)p1, (bf16)p2, (bf16)p3};
        *(bf16x4*)(prow + nb * 16) = pv;
      }
    }
    // Pw is wave-private; same-wave DS ordering suffices (no barrier).

    // O += P V
    for (int ks = 0; ks < 4; ks++) {
      bf16x8 ap0 = *(const bf16x8*)(Pw + l16 * 136 + ks * 32 + quad * 8);
      bf16x8 ap1 = *(const bf16x8*)(Pw + (16 + l16) * 136 + ks * 32 + quad * 8);
      for (int db = 0; db < 4; db++) {
        int row = db * 16 + l16;
        int slot = (ks * 4 + quad) ^ (row & 15);
        bf16x8 vf = *(const bf16x8*)(Vt + row * 128 + slot * 8);
        oc[0][db] = MFMA16(ap0, vf, oc[0][db]);
        oc[1][db] = MFMA16(ap1, vf, oc[1][db]);
      }
    }
    __syncthreads();  // protect Ks/Vt before next tile's staging
  }

  // epilogue: l(q) = 1 + sum; quad-reduce then per-row broadcast
  for (int s = 0; s < 2; s++) {
    float rtot = rs[s];
    rtot += __shfl_xor(rtot, 16);
    rtot += __shfl_xor(rtot, 32);
    float l_all = 1.f + rtot;  // lane's value is for q = (qset s, l16)
    for (int r = 0; r < 4; r++) {
      float inv = 1.f / __shfl(l_all, quad * 4 + r);
      int qrow = q0 + wave * 32 + s * 16 + quad * 4 + r;
      size_t orow = ((size_t)(b * S_ + qrow) * H_ + h) * HD_;
      for (int db = 0; db < 4; db++)
        O[orow + db * 16 + l16] = (bf16)(oc[s][db][r] * inv);
    }
  }
}

// ---------------------------------------------------------------------------
extern "C" void kernel_launch(void* const* d_in, const int* in_sizes, int n_in,
                              void* d_out, int out_size, void* d_ws,
                              size_t ws_size, hipStream_t stream) {
  const float* query = (const float*)d_in[0];
  const float* key = (const float*)d_in[1];
  const float* value = (const float*)d_in[2];
  const float* bq = (const float*)d_in[4];
  const float* bk = (const float*)d_in[6];
  const float* bv = (const float*)d_in[8];
  const float* bo = (const float*)d_in[10];
  float* out = (float*)d_out;

  // ws layout (bf16 elems): Xc[16.7M] | Qw[4M] | Kw[4M] | Vw[4M] | Ow[4M]
  bf16* Xc = (bf16*)d_ws;
  bf16* Qw = Xc + 16777216;
  const size_t SZ = (size_t)B_ * H_ * S_ * HD_;  // 4M
  bf16* Kw = Qw + SZ;
  bf16* Vw = Kw + SZ;  // V^T, [B,H,HD,S]
  bf16* Ow = Vw + SZ;  // [B,S,H,HD]

  convert_kernel<<<8192, 256, 0, stream>>>(query, key, value,
                                           (const float*)d_in[3],
                                           (const float*)d_in[5],
                                           (const float*)d_in[7],
                                           (const float*)d_in[9], Xc);
  qkv_proj_kernel<<<dim3(8, 32, 3), 256, 0, stream>>>(Xc, bq, bk, bv, Qw, Kw,
                                                      Vw);
  attn_kernel<<<512, 256, 0, stream>>>(Qw, Kw, Vw, Ow);
  out_proj_kernel<<<dim3(8, 64), 256, 0, stream>>>(Ow, Xc + 15728640, bo, out);
}

// Round 11
// 240.442 us; speedup vs baseline: 1.0763x; 1.0376x over previous
//
#include <hip/hip_runtime.h>

#define B_ 2
#define S_ 2048
#define DM_ 1024
#define H_ 16
#define HD_ 64
// Q pre-scale = HD^-0.5 * log2(e) so attention uses exp2 (bare v_exp_f32).
#define QSCALE_ 0.18033688011112042f

// Settled R0-R4: inputs fp32 (bf16-rounded values), output fp32.
typedef __bf16 bf16;
typedef __attribute__((ext_vector_type(4))) __bf16 bf16x4;
typedef __attribute__((ext_vector_type(8))) __bf16 bf16x8;
typedef __attribute__((ext_vector_type(4))) float f32x4;

#define MFMA16(a, b, c) __builtin_amdgcn_mfma_f32_16x16x32_bf16((a), (b), (c), 0, 0, 0)
#define EXP2(x) __builtin_amdgcn_exp2f(x)

__device__ __forceinline__ void async16(const bf16* g, bf16* l) {
  __builtin_amdgcn_global_load_lds(
      (const __attribute__((address_space(1))) void*)g,
      (__attribute__((address_space(3))) void*)l, 16, 0, 0);
}

// ---------------------------------------------------------------------------
// Convert pass: fp32 -> bf16, activations (3x4M) + weights (4x1M).
// ---------------------------------------------------------------------------
__global__ __launch_bounds__(256) void convert_kernel(
    const float* __restrict__ q, const float* __restrict__ k,
    const float* __restrict__ v, const float* __restrict__ wq,
    const float* __restrict__ wk, const float* __restrict__ wv,
    const float* __restrict__ wo, bf16* __restrict__ dst) {
  size_t idx = ((size_t)blockIdx.x * 256 + threadIdx.x) * 8;
  const float* src;
  size_t off;
  if (idx < 4194304) { src = q; off = idx; }
  else if (idx < 8388608) { src = k; off = idx - 4194304; }
  else if (idx < 12582912) { src = v; off = idx - 8388608; }
  else if (idx < 13631488) { src = wq; off = idx - 12582912; }
  else if (idx < 14680064) { src = wk; off = idx - 13631488; }
  else if (idx < 15728640) { src = wv; off = idx - 14680064; }
  else { src = wo; off = idx - 15728640; }
  float4 a = *(const float4*)(src + off);
  float4 b = *(const float4*)(src + off + 4);
  bf16x8 o;
  o[0] = (bf16)a.x; o[1] = (bf16)a.y; o[2] = (bf16)a.z; o[3] = (bf16)a.w;
  o[4] = (bf16)b.x; o[5] = (bf16)b.y; o[6] = (bf16)b.z; o[7] = (bf16)b.w;
  *(bf16x8*)(dst + idx) = o;
}

// ---------------------------------------------------------------------------
// GEMM 128x128, BK=64, XOR-swizzled LDS. The MODE-2 transpose buffer Ct
// ALIASES As/Bs (R10 allocated them side by side: 98KB LDS -> 1 block/CU,
// occupancy 10% -- the whole R9/R10 GEMM regression). Single 34.8KB buffer
// -> 4 blocks/CU.  __launch_bounds__(256,4) caps VGPR at 128 (was 132).
// ---------------------------------------------------------------------------
template <int MODE>
__device__ __forceinline__ void gemm_body(const bf16* A, const bf16* W,
                                          const float* bias, bf16* C,
                                          float scale) {
  constexpr int K = 1024;
  __shared__ __align__(16) bf16 smem[128 * 136];  // 34816 B, aliased
  bf16* As = smem;              // [128][64] K-loop
  bf16* Bs = smem + 128 * 64;   // [128][64] K-loop
  const int t = threadIdx.x;
  const int lane = t & 63, wave = t >> 6;
  const int quad = lane >> 4, l16 = lane & 15;
  const int m0 = blockIdx.y * 128, n0 = blockIdx.x * 128;
  const int wm = (wave >> 1) * 64, wn = (wave & 1) * 64;

  const f32x4 zero = {0.f, 0.f, 0.f, 0.f};
  f32x4 acc[4][4];
  for (int i = 0; i < 4; i++)
    for (int j = 0; j < 4; j++) acc[i][j] = zero;

  for (int k0 = 0; k0 < K; k0 += 64) {
    for (int i = 0; i < 4; ++i) {
      int c = i * 256 + t;
      int row = c >> 3, g = c & 7;
      int off = k0 + ((g ^ (row & 7)) * 8);
      async16(A + (size_t)(m0 + row) * K + off, As + c * 8);
      async16(W + (size_t)(n0 + row) * K + off, Bs + c * 8);
    }
    __syncthreads();

    for (int ks = 0; ks < 2; ks++) {
      bf16x8 af[4], bfr[4];
      for (int mb = 0; mb < 4; mb++) {
        int ra = wm + mb * 16 + l16;
        af[mb] = *(const bf16x8*)(As + ra * 64 + ((ks * 4 + quad) ^ (ra & 7)) * 8);
        int rb = wn + mb * 16 + l16;
        bfr[mb] = *(const bf16x8*)(Bs + rb * 64 + ((ks * 4 + quad) ^ (rb & 7)) * 8);
      }
      for (int mb = 0; mb < 4; mb++)
        for (int nb = 0; nb < 4; nb++)
          acc[mb][nb] = MFMA16(af[mb], bfr[nb], acc[mb][nb]);
    }
    __syncthreads();  // also makes smem safe to reuse as Ct after the loop
  }

  if constexpr (MODE == 2) {
    bf16* Ct = smem;  // [128 cols][136], reuses K-loop LDS
    for (int nb = 0; nb < 4; nb++) {
      int cl = wn + nb * 16 + l16;
      float bv = bias[n0 + cl] * scale;
      for (int mb = 0; mb < 4; mb++) {
        int rowb = wm + mb * 16 + quad * 4;
        bf16x4 v;
        for (int r = 0; r < 4; r++)
          v[r] = (bf16)(acc[mb][nb][r] * scale + bv);
        *(bf16x4*)(Ct + cl * 136 + rowb) = v;
      }
    }
    __syncthreads();
    int c = t >> 1, half = t & 1;
    int colg = n0 + c;
    int hh = colg >> 6, dd = colg & 63;
    int bb = m0 >> 11, s0 = m0 & (S_ - 1);
    bf16* dst = C + (((size_t)(bb * H_ + hh)) * HD_ + dd) * S_ + s0 + half * 64;
    const bf16* srcr = Ct + c * 136 + half * 64;
    for (int j = 0; j < 8; ++j)
      *(bf16x8*)(dst + j * 8) = *(const bf16x8*)(srcr + j * 8);
  } else {
    for (int nb = 0; nb < 4; nb++) {
      int col = n0 + wn + nb * 16 + l16;
      float bv = bias[col] * scale;
      for (int mb = 0; mb < 4; mb++) {
        int rowb = m0 + wm + mb * 16 + quad * 4;
        for (int r = 0; r < 4; r++) {
          int row = rowb + r;
          float o = acc[mb][nb][r] * scale + bv;
          int bb = row >> 11, s = row & (S_ - 1);
          int h = col >> 6, d = col & 63;
          C[(((size_t)(bb * H_ + h)) * S_ + s) * HD_ + d] = (bf16)o;
        }
      }
    }
  }
}

__global__ __launch_bounds__(256, 4) void qkv_proj_kernel(
    const bf16* Xc, const float* bq, const float* bk, const float* bv,
    bf16* Qo, bf16* Ko, bf16* Vo) {
  int z = blockIdx.z;
  const bf16* A = Xc + (size_t)z * 4194304;
  const bf16* W = Xc + 12582912 + (size_t)z * 1048576;
  if (z == 0)
    gemm_body<1>(A, W, bq, Qo, QSCALE_);  // Q pre-scaled incl. log2(e)
  else if (z == 1)
    gemm_body<1>(A, W, bk, Ko, 1.0f);
  else
    gemm_body<2>(A, W, bv, Vo, 1.0f);
}

// ---------------------------------------------------------------------------
// out_proj: 64x128 tiles (512 blocks), BK=64, swizzled. LDS 24KB.
// ---------------------------------------------------------------------------
__global__ __launch_bounds__(256) void out_proj_kernel(const bf16* A,
                                                       const bf16* W,
                                                       const float* bias,
                                                       float* C) {
  constexpr int K = 1024, N = 1024;
  __shared__ __align__(16) bf16 As[64 * 64];
  __shared__ __align__(16) bf16 Bs[128 * 64];
  const int t = threadIdx.x;
  const int lane = t & 63, wave = t >> 6;
  const int quad = lane >> 4, l16 = lane & 15;
  const int m0 = blockIdx.y * 64, n0 = blockIdx.x * 128;

  const f32x4 zero = {0.f, 0.f, 0.f, 0.f};
  f32x4 acc[8];
  for (int i = 0; i < 8; i++) acc[i] = zero;

  for (int k0 = 0; k0 < K; k0 += 64) {
    for (int i = 0; i < 2; ++i) {
      int c = i * 256 + t;
      int row = c >> 3, g = c & 7;
      async16(A + (size_t)(m0 + row) * K + k0 + ((g ^ (row & 7)) * 8),
              As + c * 8);
    }
    for (int i = 0; i < 4; ++i) {
      int c = i * 256 + t;
      int row = c >> 3, g = c & 7;
      async16(W + (size_t)(n0 + row) * K + k0 + ((g ^ (row & 7)) * 8),
              Bs + c * 8);
    }
    __syncthreads();

    for (int ks = 0; ks < 2; ks++) {
      int ra = wave * 16 + l16;
      bf16x8 af = *(const bf16x8*)(As + ra * 64 + ((ks * 4 + quad) ^ (ra & 7)) * 8);
      for (int nb = 0; nb < 8; nb++) {
        int rb = nb * 16 + l16;
        bf16x8 bfr =
            *(const bf16x8*)(Bs + rb * 64 + ((ks * 4 + quad) ^ (rb & 7)) * 8);
        acc[nb] = MFMA16(af, bfr, acc[nb]);
      }
    }
    __syncthreads();
  }

  for (int nb = 0; nb < 8; nb++) {
    int col = n0 + nb * 16 + l16;
    float bv = bias[col];
    int rowb = m0 + wave * 16 + quad * 4;
    for (int r = 0; r < 4; r++)
      C[(size_t)(rowb + r) * N + col] = acc[nb][r] + bv;
  }
}

// ---------------------------------------------------------------------------
// Flash attention, softmax-one, S^T order. Block = (b,h,128 q-rows), 4 waves
// x 32 q (2 qsets). KV tiles 128, 512 blocks. The two qsets now share ONE
// per-wave 16-row P buffer (exp->P->PV serialized per qset; wave-private,
// in-order DS pipe makes the WAR safe): LDS 67584 -> 50176 -> 3 blocks/CU
// (R7/R10 were 2). Same staging per unit work as R7 (R8 lesson), pure TLP.
// XCD-swizzled decode (id&31 -> (b,h)): per-XCD KV ~2MB L2-resident.
// exp2 (Q pre-scaled by log2e); no max-tracking; denom = 1 + sum.
// ---------------------------------------------------------------------------
__global__ __launch_bounds__(256) void attn_kernel(const bf16* __restrict__ Q,
                                                   const bf16* __restrict__ Kg,
                                                   const bf16* __restrict__ VTg,
                                                   bf16* __restrict__ O) {
  __shared__ __align__(16) bf16 Ks[128 * 64];      // XOR-swizzled granules
  __shared__ __align__(16) bf16 Vt[64 * 128];      // XOR-swizzled granules
  __shared__ __align__(16) bf16 Ps[4 * 16 * 136];  // per-wave P^T, padded
  const int t = threadIdx.x;
  const int lane = t & 63, wave = t >> 6;
  const int quad = lane >> 4, l16 = lane & 15;
  const int id = blockIdx.x;
  const int bh = id & 31;  // (b,h): fixes XCD class (id%8 = bh%8)
  const int q0 = (id >> 5) * 128;
  const int b = bh >> 4, h = bh & 15;
  const size_t base = ((size_t)(b * H_ + h)) * S_ * HD_;
  const bf16* Qp = Q + base;
  const bf16* Kp = Kg + base;
  const bf16* Vp = VTg + base;  // [HD][S]

  bf16x8 aq[2][2];
  for (int s = 0; s < 2; s++) {
    const bf16* qr = Qp + (size_t)(q0 + wave * 32 + s * 16 + l16) * HD_;
    aq[s][0] = *(const bf16x8*)(qr + quad * 8);
    aq[s][1] = *(const bf16x8*)(qr + 32 + quad * 8);
  }

  const f32x4 zero = {0.f, 0.f, 0.f, 0.f};
  f32x4 oc[2][4];
  for (int s = 0; s < 2; s++)
    for (int d = 0; d < 4; d++) oc[s][d] = zero;
  float rs[2] = {0.f, 0.f};

  bf16* Pw = Ps + wave * (16 * 136);

  for (int kv0 = 0; kv0 < S_; kv0 += 128) {
    for (int i = 0; i < 4; ++i) {
      int c = i * 256 + t;
      int row = c >> 3, g = c & 7;
      async16(Kp + (size_t)(kv0 + row) * HD_ + (g ^ (row & 7)) * 8, Ks + c * 8);
    }
    for (int i = 0; i < 4; ++i) {
      int c = i * 256 + t;
      int d = c >> 4, g = c & 15;
      async16(Vp + (size_t)d * S_ + kv0 + (g ^ (d & 15)) * 8, Vt + c * 8);
    }
    __syncthreads();

    // S^T = K Q^T: sc[s][nb][r] = S[key=kv0+nb*16+quad*4+r][q = qset s, l16]
    f32x4 sc[2][8];
    for (int s = 0; s < 2; s++)
      for (int nb = 0; nb < 8; nb++) sc[s][nb] = zero;
    for (int ks = 0; ks < 2; ks++) {
      for (int nb = 0; nb < 8; nb++) {
        int row = nb * 16 + l16;
        int slot = (ks * 4 + quad) ^ (row & 7);
        bf16x8 kf = *(const bf16x8*)(Ks + row * 64 + slot * 8);
        sc[0][nb] = MFMA16(kf, aq[0][ks], sc[0][nb]);
        sc[1][nb] = MFMA16(kf, aq[1][ks], sc[1][nb]);
      }
    }

    // per qset: exp2 + packed P^T write + per-lane partial sum, then PV.
    // Shared Pw between qsets: wave-private + in-order DS pipe -> WAR safe.
    for (int s = 0; s < 2; s++) {
      bf16* prow = Pw + l16 * 136 + quad * 4;
      for (int nb = 0; nb < 8; nb++) {
        float p0 = EXP2(sc[s][nb][0]);
        float p1 = EXP2(sc[s][nb][1]);
        float p2 = EXP2(sc[s][nb][2]);
        float p3 = EXP2(sc[s][nb][3]);
        rs[s] += (p0 + p1) + (p2 + p3);
        bf16x4 pv = {(bf16)p0, (bf16)p1, (bf16)p2, (bf16)p3};
        *(bf16x4*)(prow + nb * 16) = pv;
      }
      for (int ks = 0; ks < 4; ks++) {
        bf16x8 ap = *(const bf16x8*)(Pw + l16 * 136 + ks * 32 + quad * 8);
        for (int db = 0; db < 4; db++) {
          int row = db * 16 + l16;
          int slot = (ks * 4 + quad) ^ (row & 15);
          bf16x8 vf = *(const bf16x8*)(Vt + row * 128 + slot * 8);
          oc[s][db] = MFMA16(ap, vf, oc[s][db]);
        }
      }
    }
    __syncthreads();  // protect Ks/Vt before next tile's staging
  }

  // epilogue: l(q) = 1 + sum; quad-reduce then per-row broadcast
  for (int s = 0; s < 2; s++) {
    float rtot = rs[s];
    rtot += __shfl_xor(rtot, 16);
    rtot += __shfl_xor(rtot, 32);
    float l_all = 1.f + rtot;  // lane's value is for q = (qset s, l16)
    for (int r = 0; r < 4; r++) {
      float inv = 1.f / __shfl(l_all, quad * 4 + r);
      int qrow = q0 + wave * 32 + s * 16 + quad * 4 + r;
      size_t orow = ((size_t)(b * S_ + qrow) * H_ + h) * HD_;
      for (int db = 0; db < 4; db++)
        O[orow + db * 16 + l16] = (bf16)(oc[s][db][r] * inv);
    }
  }
}

// ---------------------------------------------------------------------------
extern "C" void kernel_launch(void* const* d_in, const int* in_sizes, int n_in,
                              void* d_out, int out_size, void* d_ws,
                              size_t ws_size, hipStream_t stream) {
  const float* query = (const float*)d_in[0];
  const float* key = (const float*)d_in[1];
  const float* value = (const float*)d_in[2];
  const float* bq = (const float*)d_in[4];
  const float* bk = (const float*)d_in[6];
  const float* bv = (const float*)d_in[8];
  const float* bo = (const float*)d_in[10];
  float* out = (float*)d_out;

  // ws layout (bf16 elems): Xc[16.7M] | Qw[4M] | Kw[4M] | Vw[4M] | Ow[4M]
  bf16* Xc = (bf16*)d_ws;
  bf16* Qw = Xc + 16777216;
  const size_t SZ = (size_t)B_ * H_ * S_ * HD_;  // 4M
  bf16* Kw = Qw + SZ;
  bf16* Vw = Kw + SZ;  // V^T, [B,H,HD,S]
  bf16* Ow = Vw + SZ;  // [B,S,H,HD]

  convert_kernel<<<8192, 256, 0, stream>>>(query, key, value,
                                           (const float*)d_in[3],
                                           (const float*)d_in[5],
                                           (const float*)d_in[7],
                                           (const float*)d_in[9], Xc);
  qkv_proj_kernel<<<dim3(8, 32, 3), 256, 0, stream>>>(Xc, bq, bk, bv, Qw, Kw,
                                                      Vw);
  attn_kernel<<<512, 256, 0, stream>>>(Qw, Kw, Vw, Ow);
  out_proj_kernel<<<dim3(8, 64), 256, 0, stream>>>(Ow, Xc + 15728640, bo, out);
}